// Round 3
// baseline (8881.795 us; speedup 1.0000x reference)
//
#include <hip/hip_runtime.h>
#include <math.h>

// TrAISformer forward, bf16-MFMA implementation (round 5).
// Round 5 changes (on the 256x256 8-phase GEMM):
//  (a) A-ring-of-3 LDS (96 KiB) + B-dbuf (64 KiB) = 160 KiB: A half-tiles
//      staged 2 K-tiles ahead (7-8 phase slack vs HBM ~900cy; round-4's
//      2-phase slack was the stall), B 1 tile ahead (L2-resident panels).
//      Stage order SA0(kt+2)@P1, SB0(kt+1)@P2, SB1(kt+1)@P3, SA1(kt+2)@P4;
//      waits vmcnt(4)@P1end + vmcnt(4)@P4end only (prefix-drain audited),
//      tails vmcnt(2)/vmcnt(0).
//  (b) W2 split-K=4 with f32 unsafeAtomicAdd into h (holds residual; bias
//      added by split 0 only): grid 64x3x4=768 = 3.0 exact CU rounds
//      (round-4: 192 blocks = 0.75 fill was 25% idle). All gemm256 calls
//      now have 12 K-tiles uniformly.

#define LNUM 12
#define HNUM 12
#define DDIM 768
#define HDIM 64
#define TSEQ 256
#define NTOK 16384
#define DFF  3072
#define QKS  1536   // fused Q|K row stride
#define NOUTC 302   // real head width
#define NOUTP 384   // padded to 3x128 tiles

typedef unsigned short u16;
typedef __attribute__((ext_vector_type(8))) __bf16 bf16x8;
typedef __attribute__((ext_vector_type(8))) unsigned short u16x8;
typedef __attribute__((ext_vector_type(4))) float f32x4;

__device__ __forceinline__ u16 f2bf(float f) {
    union { float f; unsigned u; } v; v.f = f;
    return (u16)((v.u + 0x7fff + ((v.u >> 16) & 1)) >> 16);  // RNE
}

// async global->LDS, 16B per lane; LDS dest = wave-uniform base + lane*16
__device__ __forceinline__ void gl2lds16(const u16* g, u16* l) {
    __builtin_amdgcn_global_load_lds(
        (const __attribute__((address_space(1))) void*)g,
        (__attribute__((address_space(3))) void*)l, 16, 0, 0);
}

// ---------------- embedding: four-hot concat + pos ----------------
__global__ __launch_bounds__(256)
void embed_kernel(const int* __restrict__ idxs, const float* __restrict__ lat,
                  const float* __restrict__ lon, const float* __restrict__ sog,
                  const float* __restrict__ cog, const float* __restrict__ pos,
                  float* __restrict__ h) {
    int i = blockIdx.x * 256 + threadIdx.x;           // over NTOK*DDIM, exact
    int tok = i / DDIM, d = i - tok * DDIM;
    int t = tok & (TSEQ - 1);
    int tab = d / 192, sub = d - tab * 192;
    const float* tp = (tab == 0) ? lat : (tab == 1) ? lon : (tab == 2) ? sog : cog;
    int row = idxs[tok * 4 + tab];
    h[i] = tp[row * 192 + sub] + pos[t * DDIM + d];
}

// ---------------- LayerNorm: fp32 in -> bf16 out ----------------
__global__ __launch_bounds__(256)
void ln_kernel(const float* __restrict__ in, u16* __restrict__ out,
               const float* __restrict__ g, const float* __restrict__ b) {
    const int row = blockIdx.x, t = threadIdx.x;
    const float* x = in + (size_t)row * DDIM;
    float v0 = x[t], v1 = x[t + 256], v2 = x[t + 512];
    float s = v0 + v1 + v2;
    float sq = v0 * v0 + v1 * v1 + v2 * v2;
    #pragma unroll
    for (int m = 32; m; m >>= 1) { s += __shfl_xor(s, m); sq += __shfl_xor(sq, m); }
    __shared__ float red[8];
    const int w = t >> 6;
    if ((t & 63) == 0) { red[w] = s; red[4 + w] = sq; }
    __syncthreads();
    s  = red[0] + red[1] + red[2] + red[3];
    sq = red[4] + red[5] + red[6] + red[7];
    const float mean = s * (1.f / DDIM);
    const float rstd = rsqrtf(sq * (1.f / DDIM) - mean * mean + 1e-5f);
    u16* o = out + (size_t)row * DDIM;
    o[t]       = f2bf((v0 - mean) * rstd * g[t]       + b[t]);
    o[t + 256] = f2bf((v1 - mean) * rstd * g[t + 256] + b[t + 256]);
    o[t + 512] = f2bf((v2 - mean) * rstd * g[t + 512] + b[t + 512]);
}

// ------- weight convert+transpose: fp32 [R][C] -> bf16 [Cpad][R], pad rows zero -------
__global__ __launch_bounds__(256)
void wconv_kernel(const float* __restrict__ in, u16* __restrict__ out,
                  int R, int C, int Cpad) {
    __shared__ float tile[32][33];
    const float* src = in + (size_t)blockIdx.z * R * C;
    u16* dst = out + (size_t)blockIdx.z * (size_t)Cpad * R;
    const int c0 = blockIdx.x * 32, r0 = blockIdx.y * 32;
    const int tx = threadIdx.x & 31, ty = threadIdx.x >> 5;
    #pragma unroll
    for (int i = 0; i < 4; ++i) {
        int r = r0 + ty + i * 8, c = c0 + tx;                 // r<R guaranteed (R mult of 32)
        tile[ty + i * 8][tx] = (c < C) ? src[(size_t)r * C + c] : 0.f;
    }
    __syncthreads();
    #pragma unroll
    for (int i = 0; i < 4; ++i) {
        int oc = c0 + ty + i * 8;                             // < Cpad by grid
        dst[(size_t)oc * R + r0 + tx] = f2bf(tile[tx][ty + i * 8]);
    }
}

// ================= 256x256 8-phase bf16 GEMM, A-ring3 =================
// C[M,N] = A[M,K] @ Bt[N,K]^T.  512 threads = 8 waves (wm=w>>2, wn=w&3).
// Per-wave output 128x64. Ash[3 slots][2 halves][128][64], Bsh[2][2][128][64].
// Swizzle: phys chunk = logical chunk ^ (row&7); staging keeps linear LDS
// dest and pre-permutes the per-lane GLOBAL chunk (rule 21).
// MODE 1: bf16 gelu(acc+bias) | 2: f32 out +bias+res | 5: fused QKV
//      | 6: f32 atomicAdd into Cout (+bias iff split z==0) for split-K.

#define LDA8(MQ) \
  _Pragma("unroll") for (int mt = 0; mt < 4; ++mt) { \
    a[mt][0] = __builtin_bit_cast(bf16x8, *(const u16x8*)(A0p + (MQ)*8192 + mt*1024)); \
    a[mt][1] = __builtin_bit_cast(bf16x8, *(const u16x8*)(A1p + (MQ)*8192 + mt*1024)); }

#define LDB4(NQ, BR) \
  _Pragma("unroll") for (int nt = 0; nt < 2; ++nt) { \
    BR[nt][0] = __builtin_bit_cast(bf16x8, *(const u16x8*)(B0p + (NQ)*8192 + nt*1024)); \
    BR[nt][1] = __builtin_bit_cast(bf16x8, *(const u16x8*)(B1p + (NQ)*8192 + nt*1024)); }

#define MMA16(MQ, NQ, BR) \
  __builtin_amdgcn_s_barrier(); \
  asm volatile("s_waitcnt lgkmcnt(0)" ::: "memory"); \
  __builtin_amdgcn_s_setprio(1); \
  _Pragma("unroll") for (int mt = 0; mt < 4; ++mt) \
  _Pragma("unroll") for (int nt = 0; nt < 2; ++nt) { \
    acc[(MQ)*4+mt][(NQ)*2+nt] = __builtin_amdgcn_mfma_f32_16x16x32_bf16(a[mt][0], BR[nt][0], acc[(MQ)*4+mt][(NQ)*2+nt], 0, 0, 0); \
    acc[(MQ)*4+mt][(NQ)*2+nt] = __builtin_amdgcn_mfma_f32_16x16x32_bf16(a[mt][1], BR[nt][1], acc[(MQ)*4+mt][(NQ)*2+nt], 0, 0, 0); } \
  __builtin_amdgcn_s_setprio(0);

#define STGAH(DST, H, KT) { \
  const u16* s_ = gA + (size_t)((H) * 128) * K + (size_t)(KT) * 64; \
  u16* d_ = (DST) + (H) * 8192 + w * 512; \
  gl2lds16(s_, d_); gl2lds16(s_ + (size_t)64 * K, d_ + 4096); }

#define STGBH(DST, H, KT) { \
  const u16* s_ = gB + (size_t)((H) * 128) * K + (size_t)(KT) * 64; \
  u16* d_ = (DST) + (H) * 8192 + w * 512; \
  gl2lds16(s_, d_); gl2lds16(s_ + (size_t)64 * K, d_ + 4096); }

#define VM4 asm volatile("s_waitcnt vmcnt(4)" ::: "memory");
#define VM2 asm volatile("s_waitcnt vmcnt(2)" ::: "memory");
#define VM0 asm volatile("s_waitcnt vmcnt(0)" ::: "memory");
#define VMN
#define BARR __builtin_amdgcn_s_barrier();

// Per K-tile: 4 quadrant phases (0,0),(0,1),(1,1),(1,0). Stages: A halves of
// kt+2 at P1/P4 (deep, HBM-latency-tolerant), B halves of kt+1 at P2/P3
// (shallow, L2-fed). Steady waits: vmcnt(4)@P1end (drains SB1(kt) for P2),
// vmcnt(4)@P4end (drains ...SB0(kt+1) incl. A(kt+1) for next P1/P3).
#define KTILE_S(VW1, VW4, SGA, SGB, KT) { \
  const u16* A0p = Acur + wmoff + aoff0; \
  const u16* A1p = Acur + wmoff + aoff1; \
  const u16* B0p = Bcur + wnoff + aoff0; \
  const u16* B1p = Bcur + wnoff + aoff1; \
  /*P1*/ LDA8(0) LDB4(0, b0) if (SGA) { STGAH(Astg, 0, (KT) + 2) } \
         MMA16(0, 0, b0) VW1 BARR \
  /*P2*/ LDB4(1, b1) if (SGB) { STGBH(Bstg, 0, (KT) + 1) } \
         MMA16(0, 1, b1) BARR \
  /*P3*/ LDA8(1) if (SGB) { STGBH(Bstg, 1, (KT) + 1) } \
         MMA16(1, 1, b1) BARR \
  /*P4*/ if (SGA) { STGAH(Astg, 1, (KT) + 2) } \
         MMA16(1, 0, b0) VW4 BARR \
  u16* tA_ = Acur; Acur = Anxt; Anxt = Astg; Astg = tA_; \
  u16* tB_ = Bcur; Bcur = Bstg; Bstg = tB_; \
}

template <int MODE>
__global__ __launch_bounds__(512, 2)
void gemm256(const u16* __restrict__ A, const u16* __restrict__ Bt,
             const float* __restrict__ bias, const float* __restrict__ bias2,
             const float* __restrict__ bias3, const float* __restrict__ res,
             void* __restrict__ Cout, int N, int K, int KLOC) {
    __shared__ u16 Ash[3][2][128][64] __attribute__((aligned(16)));  // 96 KiB
    __shared__ u16 Bsh[2][2][128][64] __attribute__((aligned(16)));  // 64 KiB
    const int t = threadIdx.x;
    const int w = t >> 6, l = t & 63;
    const int wm = w >> 2, wn = w & 3;
    const int fm = l & 15, fq = l >> 4;
    // bijective XCD swizzle over the full grid (nwg % 8 == 0 all launches)
    const int nwg = (int)(gridDim.x * gridDim.y * gridDim.z);
    int lin = (int)((blockIdx.z * gridDim.y + blockIdx.y) * gridDim.x + blockIdx.x);
    const int cpx = nwg >> 3;
    lin = (lin & 7) * cpx + (lin >> 3);
    const int bm = (lin & 63) * 256;                  // gridDim.x == 64 always
    const int rest = lin >> 6;
    const int bn = (rest % (int)gridDim.y) * 256;
    const int bz = rest / (int)gridDim.y;             // split-K index
    const int k0 = bz * KLOC;
    // staging per-lane source: row = w*8 + l/8; global chunk pre-permuted so
    // linear LDS dest holds phys chunk = logical ^ (row&7).
    const int srow = (w << 3) + (l >> 3);
    const int schunk = (l & 7) ^ ((l >> 3) & 7);
    const u16* gA = A + (size_t)(bm + srow) * K + k0 + schunk * 8;
    const u16* gB = Bt + (size_t)(bn + srow) * K + k0 + schunk * 8;
    // ds_read per-lane offsets; read chunk = (ks*4+fq) ^ (fm&7)
    const int aoff0 = fm * 64 + ((fq ^ (fm & 7)) << 3);
    const int aoff1 = aoff0 ^ 32;                     // ks=1 flips chunk bit2
    const int wmoff = wm * 4096, wnoff = wn * 2048;
    u16* Acur = &Ash[0][0][0][0];
    u16* Anxt = &Ash[1][0][0][0];
    u16* Astg = &Ash[2][0][0][0];
    u16* Bcur = &Bsh[0][0][0][0];
    u16* Bstg = &Bsh[1][0][0][0];
    f32x4 acc[8][4];
    #pragma unroll
    for (int i = 0; i < 8; ++i)
        #pragma unroll
        for (int j = 0; j < 4; ++j) acc[i][j] = (f32x4){0.f, 0.f, 0.f, 0.f};
    bf16x8 a[4][2], b0[2][2], b1[2][2];
    // prologue: A(0), B(0), A(1); drain A(0)+B(0), keep A(1) in flight (4).
    STGAH(Acur, 0, 0) STGAH(Acur, 1, 0)
    STGBH(Bcur, 0, 0) STGBH(Bcur, 1, 0)
    STGAH(Anxt, 0, 1) STGAH(Anxt, 1, 1)
    VM4
    BARR
    const int nloc = KLOC >> 6;                       // 12 for all call sites
    int kt = 0;
    for (; kt <= nloc - 3; ++kt) {                    // steady: full staging
        KTILE_S(VM4, VM4, true, true, kt)
    }
    KTILE_S(VM2, VM2, false, true, kt)                // kt = nloc-2: B only
    ++kt;
    KTILE_S(VM0, VMN, false, false, kt)               // kt = nloc-1: no stage
    // epilogue: acc[m8][n4] -> row = bm + (m8>>2)*128 + wm*64 + (m8&3)*16 + fq*4+i
    //                          col = bn + (n4>>1)*128 + wn*32 + (n4&1)*16 + fm
    #pragma unroll
    for (int m8 = 0; m8 < 8; ++m8) {
        const int row0 = bm + (m8 >> 2) * 128 + wm * 64 + (m8 & 3) * 16 + fq * 4;
        #pragma unroll
        for (int n4 = 0; n4 < 4; ++n4) {
            const int col = bn + (n4 >> 1) * 128 + wn * 32 + (n4 & 1) * 16 + fm;
            float bv;
            if (MODE == 5) {
                bv = (col < 768) ? bias[col] : (col < 1536) ? bias2[col - 768] : bias3[col - 1536];
            } else {
                bv = bias[col];
            }
            #pragma unroll
            for (int i = 0; i < 4; ++i) {
                const int row = row0 + i;
                float v = acc[m8][n4][i] + bv;
                if (MODE == 1) {
                    v = 0.5f * v * (1.f + erff(v * 0.70710678118654752f));  // exact gelu
                    ((u16*)Cout)[(size_t)row * N + col] = f2bf(v);
                } else if (MODE == 2) {
                    ((float*)Cout)[(size_t)row * N + col] = v + res[(size_t)row * N + col];
                } else if (MODE == 6) {
                    // split-K: Cout already holds residual; bias from split 0 only
                    float av = acc[m8][n4][i] + (bz == 0 ? bv : 0.f);
                    unsafeAtomicAdd((float*)Cout + (size_t)row * N + col, av);
                } else {  // MODE 5
                    if (col < 1536) {
                        ((u16*)Cout)[(size_t)row * QKS + col] = f2bf(v);
                    } else {           // V^T scatter -> Vt[(b*H+h)][d][t]
                        const int c = col - 1536;
                        const int bb = row >> 8, tt = row & 255;
                        const int hh = c >> 6, dd = c & 63;
                        u16* vt = (u16*)Cout + (size_t)NTOK * QKS;
                        vt[(((size_t)(bb * HNUM + hh)) * HDIM + dd) * TSEQ + tt] = f2bf(v);
                    }
                }
            }
        }
    }
}

// ---------------- bf16 GEMM 128x128 (ring-3, kept for head N=384) ----------------
template <int MODE>
__global__ __launch_bounds__(256)
void gemm_bt(const u16* __restrict__ A, const u16* __restrict__ Bt,
             const float* __restrict__ bias, const float* __restrict__ bias2,
             const float* __restrict__ bias3, const float* __restrict__ res,
             void* __restrict__ Cout, int M, int N, int K, int ncut) {
    __shared__ u16 As[3][128][32] __attribute__((aligned(16)));
    __shared__ u16 Bs[3][128][32] __attribute__((aligned(16)));
    const int t = threadIdx.x;
    const int w = t >> 6, lane = t & 63;
    const int bm = blockIdx.x * 128, bn = blockIdx.y * 128;
    const int moff = (w >> 1) * 64, noff = (w & 1) * 64;
    const int lrow = t >> 2;
    const int fm = lane & 15, fq = lane >> 4;
    const f32x4 zero = {0.f, 0.f, 0.f, 0.f};
    f32x4 acc[4][4];
    #pragma unroll
    for (int a = 0; a < 4; ++a)
        #pragma unroll
        for (int c = 0; c < 4; ++c) acc[a][c] = zero;
    const u16* pA = A + (size_t)(bm + lrow) * K + (t & 3) * 8;
    const u16* pB = Bt + (size_t)(bn + lrow) * K + (t & 3) * 8;
    const size_t rstep = (size_t)64 * K;
    const int wr = w << 4;
    auto stage = [&](int s, int b) {
        const u16* ga = pA + s * 32;
        const u16* gb = pB + s * 32;
        gl2lds16(ga,         &As[b][wr][0]);
        gl2lds16(ga + rstep, &As[b][wr + 64][0]);
        gl2lds16(gb,         &Bs[b][wr][0]);
        gl2lds16(gb + rstep, &Bs[b][wr + 64][0]);
    };
    const int kts = K >> 5;
    stage(0, 0);
    stage(1, 1);
    int bcur = 0, bpre = 2;
    for (int kt = 0; kt < kts; ++kt) {
        if (kt + 2 < kts) stage(kt + 2, bpre);
        const int ahead = kts - 1 - kt;
        if (ahead >= 2)      asm volatile("s_waitcnt vmcnt(8)" ::: "memory");
        else if (ahead == 1) asm volatile("s_waitcnt vmcnt(4)" ::: "memory");
        else                 asm volatile("s_waitcnt vmcnt(0)" ::: "memory");
        __builtin_amdgcn_s_barrier();
        bf16x8 af[4], bfr[4];
        #pragma unroll
        for (int mt = 0; mt < 4; ++mt)
            af[mt] = __builtin_bit_cast(bf16x8, *(const u16x8*)&As[bcur][moff + mt * 16 + fm][fq * 8]);
        #pragma unroll
        for (int nt = 0; nt < 4; ++nt)
            bfr[nt] = __builtin_bit_cast(bf16x8, *(const u16x8*)&Bs[bcur][noff + nt * 16 + fm][fq * 8]);
        asm volatile("s_waitcnt lgkmcnt(0)" ::: "memory");
        __builtin_amdgcn_s_barrier();
        #pragma unroll
        for (int mt = 0; mt < 4; ++mt)
            #pragma unroll
            for (int nt = 0; nt < 4; ++nt)
                acc[mt][nt] = __builtin_amdgcn_mfma_f32_16x16x32_bf16(af[mt], bfr[nt], acc[mt][nt], 0, 0, 0);
        bcur = (bcur == 2) ? 0 : bcur + 1;
        bpre = (bpre == 2) ? 0 : bpre + 1;
    }
    #pragma unroll
    for (int mt = 0; mt < 4; ++mt) {
        #pragma unroll
        for (int nt = 0; nt < 4; ++nt) {
            const int col = bn + noff + nt * 16 + fm;
            float bv = 0.f;
            if (MODE != 3) bv = bias[col];
            #pragma unroll
            for (int i = 0; i < 4; ++i) {
                const int row = bm + moff + mt * 16 + fq * 4 + i;
                float v = acc[mt][nt][i] + bv;
                if (MODE == 0) {
                    ((u16*)Cout)[(size_t)row * N + col] = f2bf(v);
                } else if (MODE == 2) {
                    ((float*)Cout)[(size_t)row * N + col] = v + res[(size_t)row * N + col];
                } else if (MODE == 3) {
                    if (col < ncut) ((float*)Cout)[(size_t)row * ncut + col] = v;
                }
            }
        }
    }
}

// ---------------- fused causal attention ----------------
__global__ __launch_bounds__(256)
void attn_kernel(const u16* __restrict__ QK, const u16* __restrict__ Vt,
                 u16* __restrict__ Yb) {
    __shared__ u16 Pt[4][256][16] __attribute__((aligned(16)));  // [wave][kcol][qrow]
    const int bh = blockIdx.x;
    const int b = bh / HNUM, hh = bh - b * HNUM;
    const int w = threadIdx.x >> 6, lane = threadIdx.x & 63;
    const int fm = lane & 15, fq = lane >> 4;
    const int qt = blockIdx.y * 4 + w;
    const size_t qrow0 = (size_t)b * TSEQ;
    const int col0 = hh * HDIM;
    const u16* qp = QK + (qrow0 + qt * 16 + fm) * QKS + col0 + fq * 8;
    const bf16x8 aq0 = __builtin_bit_cast(bf16x8, *(const u16x8*)qp);
    const bf16x8 aq1 = __builtin_bit_cast(bf16x8, *(const u16x8*)(qp + 32));
    f32x4 s[16];
    #pragma unroll
    for (int kt = 0; kt < 16; ++kt) {
        if (kt <= qt) {
            const u16* kp = QK + (qrow0 + kt * 16 + fm) * QKS + 768 + col0 + fq * 8;
            bf16x8 bk0 = __builtin_bit_cast(bf16x8, *(const u16x8*)kp);
            bf16x8 bk1 = __builtin_bit_cast(bf16x8, *(const u16x8*)(kp + 32));
            f32x4 z = {0.f, 0.f, 0.f, 0.f};
            z = __builtin_amdgcn_mfma_f32_16x16x32_bf16(aq0, bk0, z, 0, 0, 0);
            z = __builtin_amdgcn_mfma_f32_16x16x32_bf16(aq1, bk1, z, 0, 0, 0);
            s[kt] = z;
        }
    }
    float lrow[4];
    #pragma unroll
    for (int i = 0; i < 4; ++i) {
        float mx = -1e30f;
        #pragma unroll
        for (int kt = 0; kt < 16; ++kt) {
            if (kt <= qt) {
                const bool valid = (kt < qt) || (fm <= fq * 4 + i);
                const float v = valid ? s[kt][i] * 0.125f : -1e30f;
                s[kt][i] = v;
                mx = fmaxf(mx, v);
            }
        }
        #pragma unroll
        for (int d = 1; d < 16; d <<= 1) mx = fmaxf(mx, __shfl_xor(mx, d));
        float sum = 0.f;
        #pragma unroll
        for (int kt = 0; kt < 16; ++kt) {
            if (kt <= qt) {
                const float e = __expf(s[kt][i] - mx);
                s[kt][i] = e;
                sum += e;
            }
        }
        #pragma unroll
        for (int d = 1; d < 16; d <<= 1) sum += __shfl_xor(sum, d);
        lrow[i] = sum;
    }
    const int nks = (qt + 2) >> 1;
    #pragma unroll
    for (int kt = 0; kt < 16; ++kt) {
        if (kt < 2 * nks) {
            unsigned lo = 0, hi = 0;
            if (kt <= qt) {
                lo = (unsigned)f2bf(s[kt][0]) | ((unsigned)f2bf(s[kt][1]) << 16);
                hi = (unsigned)f2bf(s[kt][2]) | ((unsigned)f2bf(s[kt][3]) << 16);
            }
            uint2 pk; pk.x = lo; pk.y = hi;
            *(uint2*)&Pt[w][kt * 16 + fm][fq * 4] = pk;
        }
    }
    __syncthreads();
    f32x4 o[4];
    #pragma unroll
    for (int dt = 0; dt < 4; ++dt) o[dt] = (f32x4){0.f, 0.f, 0.f, 0.f};
    #pragma unroll
    for (int ks = 0; ks < 8; ++ks) {
        if (ks < nks) {
            u16x8 praw;
            #pragma unroll
            for (int j = 0; j < 8; ++j) praw[j] = Pt[w][ks * 32 + fq * 8 + j][fm];
            const bf16x8 pa = __builtin_bit_cast(bf16x8, praw);
            #pragma unroll
            for (int dt = 0; dt < 4; ++dt) {
                const u16* vp = Vt + ((size_t)bh * HDIM + dt * 16 + fm) * TSEQ + ks * 32 + fq * 8;
                const bf16x8 bv = __builtin_bit_cast(bf16x8, *(const u16x8*)vp);
                o[dt] = __builtin_amdgcn_mfma_f32_16x16x32_bf16(pa, bv, o[dt], 0, 0, 0);
            }
        }
    }
    #pragma unroll
    for (int i = 0; i < 4; ++i) {
        const float inv = 1.f / lrow[i];
        #pragma unroll
        for (int dt = 0; dt < 4; ++dt)
            Yb[(qrow0 + qt * 16 + fq * 4 + i) * DDIM + col0 + dt * 16 + fm] = f2bf(o[dt][i] * inv);
    }
}

extern "C" void kernel_launch(void* const* d_in, const int* in_sizes, int n_in,
                              void* d_out, int out_size, void* d_ws, size_t ws_size,
                              hipStream_t stream) {
    (void)in_sizes; (void)n_in; (void)out_size; (void)ws_size;
    const int*   idxs  = (const int*)d_in[0];
    const float* lat   = (const float*)d_in[1];
    const float* lon   = (const float*)d_in[2];
    const float* sog   = (const float*)d_in[3];
    const float* cog   = (const float*)d_in[4];
    const float* pos   = (const float*)d_in[5];
    const float* ln1_g = (const float*)d_in[6];
    const float* ln1_b = (const float*)d_in[7];
    const float* ln2_g = (const float*)d_in[8];
    const float* ln2_b = (const float*)d_in[9];
    const float* Wq = (const float*)d_in[10];
    const float* bq = (const float*)d_in[11];
    const float* Wk = (const float*)d_in[12];
    const float* bk = (const float*)d_in[13];
    const float* Wv = (const float*)d_in[14];
    const float* bv = (const float*)d_in[15];
    const float* Wo = (const float*)d_in[16];
    const float* bo = (const float*)d_in[17];
    const float* W1 = (const float*)d_in[18];
    const float* b1 = (const float*)d_in[19];
    const float* W2 = (const float*)d_in[20];
    const float* b2 = (const float*)d_in[21];
    const float* lnf_g = (const float*)d_in[22];
    const float* lnf_b = (const float*)d_in[23];
    const float* Whead = (const float*)d_in[24];

    // workspace carve (~191 MB). ub overlays qk|vt|yb (NTOK*1536 + 2*NTOK*768 == NTOK*DFF bf16).
    char* base = (char*)d_ws;
    size_t off = 0;
    auto carve = [&](size_t bytes) { void* r = base + off; off += (bytes + 255) & ~(size_t)255; return r; };
    float* h  = (float*)carve((size_t)NTOK * DDIM * 4);
    u16* xb = (u16*)carve((size_t)NTOK * DDIM * 2);
    u16* qk = (u16*)carve((size_t)NTOK * QKS * 2);    // fused Q|K
    u16* vt = (u16*)carve((size_t)NTOK * DDIM * 2);   // V^T   (must follow qk: MODE5 offsets)
    u16* yb = (u16*)carve((size_t)NTOK * DDIM * 2);
    u16* ub = qk;  // contiguous overlay [NTOK][DFF]
    u16* WtQKV = (u16*)carve((size_t)3 * DDIM * DDIM * 2);  // concat rows: Q|K|V
    u16* WtO = (u16*)carve((size_t)DDIM * DDIM * 2);
    u16* Wt1 = (u16*)carve((size_t)DDIM * DFF * 2);
    u16* Wt2 = (u16*)carve((size_t)DFF * DDIM * 2);
    u16* WtH = (u16*)carve((size_t)NOUTP * DDIM * 2);

    embed_kernel<<<NTOK * DDIM / 256, 256, 0, stream>>>(idxs, lat, lon, sog, cog, pos, h);

    // gemm256 grids: x = M-tile (64, fast), y = N-tile, z = K-split. All nwg%8==0,
    // all K-loops = 12 tiles. W2: 64x3x4 = 768 = 3.0 exact CU rounds (split-K=4).
    const dim3 G768(64, 3, 1), G3072(64, 12, 1), GQKV(64, 9, 1), GW2(64, 3, 4), ghead(128, 3);
    const dim3 tq(24, 24, 1), t1(96, 24, 1), t2(24, 96, 1);
    const size_t wsq = (size_t)DDIM * DDIM, wsf = (size_t)DDIM * DFF;
    for (int l = 0; l < LNUM; ++l) {
        wconv_kernel<<<tq, 256, 0, stream>>>(Wq + l * wsq, WtQKV, DDIM, DDIM, DDIM);
        wconv_kernel<<<tq, 256, 0, stream>>>(Wk + l * wsq, WtQKV + wsq, DDIM, DDIM, DDIM);
        wconv_kernel<<<tq, 256, 0, stream>>>(Wv + l * wsq, WtQKV + 2 * wsq, DDIM, DDIM, DDIM);
        wconv_kernel<<<tq, 256, 0, stream>>>(Wo + l * wsq, WtO, DDIM, DDIM, DDIM);
        wconv_kernel<<<t1, 256, 0, stream>>>(W1 + l * wsf, Wt1, DDIM, DFF, DFF);
        wconv_kernel<<<t2, 256, 0, stream>>>(W2 + l * wsf, Wt2, DFF, DDIM, DDIM);

        ln_kernel<<<NTOK, 256, 0, stream>>>(h, xb, ln1_g + l * DDIM, ln1_b + l * DDIM);
        gemm256<5><<<GQKV, 512, 0, stream>>>(xb, WtQKV, bq + l * DDIM, bk + l * DDIM,
                                             bv + l * DDIM, nullptr, qk,
                                             3 * DDIM, DDIM, DDIM);
        attn_kernel<<<dim3(768, 4), 256, 0, stream>>>(qk, vt, yb);
        gemm256<2><<<G768, 512, 0, stream>>>(yb, WtO, bo + l * DDIM, nullptr, nullptr, h, h,
                                             DDIM, DDIM, DDIM);
        ln_kernel<<<NTOK, 256, 0, stream>>>(h, xb, ln2_g + l * DDIM, ln2_b + l * DDIM);
        gemm256<1><<<G3072, 512, 0, stream>>>(xb, Wt1, b1 + l * DFF, nullptr, nullptr, nullptr, ub,
                                              DFF, DDIM, DDIM);
        gemm256<6><<<GW2, 512, 0, stream>>>(ub, Wt2, b2 + l * DDIM, nullptr, nullptr, nullptr, h,
                                            DDIM, DFF, DFF / 4);
    }
    ln_kernel<<<NTOK, 256, 0, stream>>>(h, xb, lnf_g, lnf_b);
    wconv_kernel<<<dim3(NOUTP / 32, DDIM / 32, 1), 256, 0, stream>>>(Whead, WtH, DDIM, NOUTC, NOUTP);
    gemm_bt<3><<<ghead, 256, 0, stream>>>(xb, WtH, nullptr, nullptr, nullptr, nullptr, d_out,
                                          NTOK, NOUTP, DDIM, NOUTC);
}

// Round 5
// 6600.327 us; speedup vs baseline: 1.3457x; 1.3457x over previous
//
#include <hip/hip_runtime.h>
#include <math.h>

// TrAISformer forward, bf16-MFMA implementation (round 6, resubmitted r7).
// Round-4 bench was an infra failure ("container failed twice", no counters);
// kernel re-audited (pipeline WAR/RAW, barrier uniformity, wconv4 bounds) and
// resubmitted unchanged to get the round-6 measurement.
// Round 6: revert to the verified-best R3 128x128 ring GEMM, with two changes:
//  (a) LDS 2-buffer (32 KiB, was ring-3 48 KiB), prefetch depth 1, counted
//      vmcnt(4): raises residency 3 -> 4 blocks/CU (16 waves/CU). R2/R3/R4
//      all landed ~150us for W2 under different schedules with everything
//      idle (Mfma ~20%, VALU ~13%, HBM 16%) => latency/TLP-bound; blocks/CU
//      is the untouched lever (m114 mechanism). WAR safety: buf^1's reads
//      finish at the lgkm+barrier one full K-step before the overwriting
//      stage is issued.
//  (b) Q/K/V/O weight transposes fused into one z=4 launch (13 -> 10
//      launches per layer).
//  8-phase 256^2 (R4/R5) abandoned: measured neutral-to-worse at 1 blk/CU.

#define LNUM 12
#define HNUM 12
#define DDIM 768
#define HDIM 64
#define TSEQ 256
#define NTOK 16384
#define DFF  3072
#define QKS  1536   // fused Q|K row stride
#define NOUTC 302   // real head width
#define NOUTP 384   // padded to 3x128 tiles

typedef unsigned short u16;
typedef __attribute__((ext_vector_type(8))) __bf16 bf16x8;
typedef __attribute__((ext_vector_type(8))) unsigned short u16x8;
typedef __attribute__((ext_vector_type(4))) float f32x4;

__device__ __forceinline__ u16 f2bf(float f) {
    union { float f; unsigned u; } v; v.f = f;
    return (u16)((v.u + 0x7fff + ((v.u >> 16) & 1)) >> 16);  // RNE
}

// async global->LDS, 16B per lane; LDS dest = wave-uniform base + lane*16
__device__ __forceinline__ void gl2lds16(const u16* g, u16* l) {
    __builtin_amdgcn_global_load_lds(
        (const __attribute__((address_space(1))) void*)g,
        (__attribute__((address_space(3))) void*)l, 16, 0, 0);
}

// ---------------- embedding: four-hot concat + pos ----------------
__global__ __launch_bounds__(256)
void embed_kernel(const int* __restrict__ idxs, const float* __restrict__ lat,
                  const float* __restrict__ lon, const float* __restrict__ sog,
                  const float* __restrict__ cog, const float* __restrict__ pos,
                  float* __restrict__ h) {
    int i = blockIdx.x * 256 + threadIdx.x;           // over NTOK*DDIM, exact
    int tok = i / DDIM, d = i - tok * DDIM;
    int t = tok & (TSEQ - 1);
    int tab = d / 192, sub = d - tab * 192;
    const float* tp = (tab == 0) ? lat : (tab == 1) ? lon : (tab == 2) ? sog : cog;
    int row = idxs[tok * 4 + tab];
    h[i] = tp[row * 192 + sub] + pos[t * DDIM + d];
}

// ---------------- LayerNorm: fp32 in -> bf16 out ----------------
__global__ __launch_bounds__(256)
void ln_kernel(const float* __restrict__ in, u16* __restrict__ out,
               const float* __restrict__ g, const float* __restrict__ b) {
    const int row = blockIdx.x, t = threadIdx.x;
    const float* x = in + (size_t)row * DDIM;
    float v0 = x[t], v1 = x[t + 256], v2 = x[t + 512];
    float s = v0 + v1 + v2;
    float sq = v0 * v0 + v1 * v1 + v2 * v2;
    #pragma unroll
    for (int m = 32; m; m >>= 1) { s += __shfl_xor(s, m); sq += __shfl_xor(sq, m); }
    __shared__ float red[8];
    const int w = t >> 6;
    if ((t & 63) == 0) { red[w] = s; red[4 + w] = sq; }
    __syncthreads();
    s  = red[0] + red[1] + red[2] + red[3];
    sq = red[4] + red[5] + red[6] + red[7];
    const float mean = s * (1.f / DDIM);
    const float rstd = rsqrtf(sq * (1.f / DDIM) - mean * mean + 1e-5f);
    u16* o = out + (size_t)row * DDIM;
    o[t]       = f2bf((v0 - mean) * rstd * g[t]       + b[t]);
    o[t + 256] = f2bf((v1 - mean) * rstd * g[t + 256] + b[t + 256]);
    o[t + 512] = f2bf((v2 - mean) * rstd * g[t + 512] + b[t + 512]);
}

// ------- weight convert+transpose: fp32 [R][C] -> bf16 [Cpad][R], pad rows zero -------
__global__ __launch_bounds__(256)
void wconv_kernel(const float* __restrict__ in, u16* __restrict__ out,
                  int R, int C, int Cpad) {
    __shared__ float tile[32][33];
    const float* src = in + (size_t)blockIdx.z * R * C;
    u16* dst = out + (size_t)blockIdx.z * (size_t)Cpad * R;
    const int c0 = blockIdx.x * 32, r0 = blockIdx.y * 32;
    const int tx = threadIdx.x & 31, ty = threadIdx.x >> 5;
    #pragma unroll
    for (int i = 0; i < 4; ++i) {
        int r = r0 + ty + i * 8, c = c0 + tx;                 // r<R guaranteed (R mult of 32)
        tile[ty + i * 8][tx] = (c < C) ? src[(size_t)r * C + c] : 0.f;
    }
    __syncthreads();
    #pragma unroll
    for (int i = 0; i < 4; ++i) {
        int oc = c0 + ty + i * 8;                             // < Cpad by grid
        dst[(size_t)oc * R + r0 + tx] = f2bf(tile[tx][ty + i * 8]);
    }
}

// ------- fused Q/K/V/O transpose: 4 square 768x768 weights in one launch -------
__global__ __launch_bounds__(256)
void wconv4_kernel(const float* __restrict__ Wq, const float* __restrict__ Wk,
                   const float* __restrict__ Wv, const float* __restrict__ Wo,
                   u16* __restrict__ WtQKV, u16* __restrict__ WtO) {
    __shared__ float tile[32][33];
    const int z = blockIdx.z;                                 // 0=Q 1=K 2=V 3=O
    const float* src = (z == 0) ? Wq : (z == 1) ? Wk : (z == 2) ? Wv : Wo;
    u16* dst = (z < 3) ? WtQKV + (size_t)z * DDIM * DDIM : WtO;
    const int c0 = blockIdx.x * 32, r0 = blockIdx.y * 32;
    const int tx = threadIdx.x & 31, ty = threadIdx.x >> 5;
    #pragma unroll
    for (int i = 0; i < 4; ++i)
        tile[ty + i * 8][tx] = src[(size_t)(r0 + ty + i * 8) * DDIM + c0 + tx];
    __syncthreads();
    #pragma unroll
    for (int i = 0; i < 4; ++i)
        dst[(size_t)(c0 + ty + i * 8) * DDIM + r0 + tx] = f2bf(tile[tx][ty + i * 8]);
}

// ---------------- bf16 GEMM: C[M,N] = A[M,K] @ Bt[N,K]^T ----------------
// 128x128 tile, BK=32, 4 waves 2x2, mfma_f32_16x16x32_bf16, fp32 acc.
// 2-buffer LDS (32 KiB), prefetch depth 1, counted vmcnt(4) (drain only the
// tile about to be consumed; the prefetch stays in flight across barriers).
// Grid: blockIdx.x = M-tile (fast), blockIdx.y = N-tile (slow) -> B L2-resident.
// MODE 0: bf16 out +bias | 1: bf16 gelu(acc+bias) | 2: f32 out +bias+res
//      3: f32 out, col<ncut, ld=ncut (head)
//      5: fused QKV: col<1536 -> bf16 qk[row*1536+col] (+bq/bk); else V^T scatter (+bv)
template <int MODE>
__global__ __launch_bounds__(256)
void gemm_bt(const u16* __restrict__ A, const u16* __restrict__ Bt,
             const float* __restrict__ bias, const float* __restrict__ bias2,
             const float* __restrict__ bias3, const float* __restrict__ res,
             void* __restrict__ Cout, int M, int N, int K, int ncut) {
    __shared__ u16 As[2][128][32] __attribute__((aligned(16)));
    __shared__ u16 Bs[2][128][32] __attribute__((aligned(16)));
    const int t = threadIdx.x;
    const int w = t >> 6, lane = t & 63;
    const int bm = blockIdx.x * 128, bn = blockIdx.y * 128;   // M fast, N slow
    const int moff = (w >> 1) * 64, noff = (w & 1) * 64;
    const int lrow = t >> 2;
    const int fm = lane & 15, fq = lane >> 4;
    const f32x4 zero = {0.f, 0.f, 0.f, 0.f};
    f32x4 acc[4][4];
    #pragma unroll
    for (int a = 0; a < 4; ++a)
        #pragma unroll
        for (int c = 0; c < 4; ++c) acc[a][c] = zero;
    const u16* pA = A + (size_t)(bm + lrow) * K + (t & 3) * 8;
    const u16* pB = Bt + (size_t)(bn + lrow) * K + (t & 3) * 8;
    const size_t rstep = (size_t)64 * K;
    const int wr = w << 4;   // wave w stages rows wr..wr+15 and 64+wr..64+wr+15
    auto stage = [&](int s, int b) {
        const u16* ga = pA + s * 32;
        const u16* gb = pB + s * 32;
        gl2lds16(ga,         &As[b][wr][0]);
        gl2lds16(ga + rstep, &As[b][wr + 64][0]);
        gl2lds16(gb,         &Bs[b][wr][0]);
        gl2lds16(gb + rstep, &Bs[b][wr + 64][0]);
    };
    const int kts = K >> 5;                 // K mult of 32, kts >= 2 always here
    stage(0, 0);
    for (int kt = 0; kt < kts; ++kt) {
        const int cur = kt & 1;
        if (kt + 1 < kts) {
            stage(kt + 1, cur ^ 1);          // prefetch into the other buffer
            asm volatile("s_waitcnt vmcnt(4)" ::: "memory");  // drain tile kt only
        } else {
            asm volatile("s_waitcnt vmcnt(0)" ::: "memory");
        }
        __builtin_amdgcn_s_barrier();        // tile kt visible to all waves
        bf16x8 af[4], bfr[4];
        #pragma unroll
        for (int mt = 0; mt < 4; ++mt)
            af[mt] = __builtin_bit_cast(bf16x8, *(const u16x8*)&As[cur][moff + mt * 16 + fm][fq * 8]);
        #pragma unroll
        for (int nt = 0; nt < 4; ++nt)
            bfr[nt] = __builtin_bit_cast(bf16x8, *(const u16x8*)&Bs[cur][noff + nt * 16 + fm][fq * 8]);
        asm volatile("s_waitcnt lgkmcnt(0)" ::: "memory");
        __builtin_amdgcn_s_barrier();        // reads done: next stage may overwrite cur
        #pragma unroll
        for (int mt = 0; mt < 4; ++mt)
            #pragma unroll
            for (int nt = 0; nt < 4; ++nt)
                acc[mt][nt] = __builtin_amdgcn_mfma_f32_16x16x32_bf16(af[mt], bfr[nt], acc[mt][nt], 0, 0, 0);
    }
    #pragma unroll
    for (int mt = 0; mt < 4; ++mt) {
        #pragma unroll
        for (int nt = 0; nt < 4; ++nt) {
            const int col = bn + noff + nt * 16 + fm;
            float bv = 0.f;
            if (MODE == 5) {
                bv = (col < 768) ? bias[col] : (col < 1536) ? bias2[col - 768] : bias3[col - 1536];
            } else if (MODE != 3) {
                bv = bias[col];
            }
            #pragma unroll
            for (int i = 0; i < 4; ++i) {
                const int row = bm + moff + mt * 16 + fq * 4 + i;  // C/D: row=quad*4+reg, col=lane&15
                float v = acc[mt][nt][i] + bv;
                if (MODE == 0) {
                    ((u16*)Cout)[(size_t)row * N + col] = f2bf(v);
                } else if (MODE == 1) {
                    v = 0.5f * v * (1.f + erff(v * 0.70710678118654752f));  // exact gelu
                    ((u16*)Cout)[(size_t)row * N + col] = f2bf(v);
                } else if (MODE == 2) {
                    ((float*)Cout)[(size_t)row * N + col] = v + res[(size_t)row * N + col];
                } else if (MODE == 3) {
                    if (col < ncut) ((float*)Cout)[(size_t)row * ncut + col] = v;
                } else {  // MODE 5
                    if (col < 1536) {
                        ((u16*)Cout)[(size_t)row * QKS + col] = f2bf(v);
                    } else {           // V^T scatter -> Vt[(b*H+h)][d][t], Vt = Cout+ntok*1536
                        const int c = col - 1536;
                        const int bb = row >> 8, tt = row & 255;
                        const int hh = c >> 6, dd = c & 63;
                        u16* vt = (u16*)Cout + (size_t)NTOK * QKS;
                        vt[(((size_t)(bb * HNUM + hh)) * HDIM + dd) * TSEQ + tt] = f2bf(v);
                    }
                }
            }
        }
    }
}

// ---------------- fused causal attention ----------------
// grid (B*H, 4), block 256 = 4 waves; wave w -> query tile qt = by*4+w (16 rows).
// Q,K read from fused qk buffer (row stride 1536; K at col offset 768).
__global__ __launch_bounds__(256)
void attn_kernel(const u16* __restrict__ QK, const u16* __restrict__ Vt,
                 u16* __restrict__ Yb) {
    __shared__ u16 Pt[4][256][16] __attribute__((aligned(16)));  // [wave][kcol][qrow]
    const int bh = blockIdx.x;
    const int b = bh / HNUM, hh = bh - b * HNUM;
    const int w = threadIdx.x >> 6, lane = threadIdx.x & 63;
    const int fm = lane & 15, fq = lane >> 4;
    const int qt = blockIdx.y * 4 + w;
    const size_t qrow0 = (size_t)b * TSEQ;
    const int col0 = hh * HDIM;
    const u16* qp = QK + (qrow0 + qt * 16 + fm) * QKS + col0 + fq * 8;
    const bf16x8 aq0 = __builtin_bit_cast(bf16x8, *(const u16x8*)qp);        // k 0..31
    const bf16x8 aq1 = __builtin_bit_cast(bf16x8, *(const u16x8*)(qp + 32)); // k 32..63
    f32x4 s[16];
    #pragma unroll
    for (int kt = 0; kt < 16; ++kt) {
        if (kt <= qt) {                                   // causal tile skip (wave-uniform)
            const u16* kp = QK + (qrow0 + kt * 16 + fm) * QKS + 768 + col0 + fq * 8;
            bf16x8 bk0 = __builtin_bit_cast(bf16x8, *(const u16x8*)kp);
            bf16x8 bk1 = __builtin_bit_cast(bf16x8, *(const u16x8*)(kp + 32));
            f32x4 z = {0.f, 0.f, 0.f, 0.f};
            z = __builtin_amdgcn_mfma_f32_16x16x32_bf16(aq0, bk0, z, 0, 0, 0);
            z = __builtin_amdgcn_mfma_f32_16x16x32_bf16(aq1, bk1, z, 0, 0, 0);
            s[kt] = z;
        }
    }
    float lrow[4];
    #pragma unroll
    for (int i = 0; i < 4; ++i) {                         // row r = fq*4+i
        float mx = -1e30f;
        #pragma unroll
        for (int kt = 0; kt < 16; ++kt) {
            if (kt <= qt) {
                const bool valid = (kt < qt) || (fm <= fq * 4 + i);  // diag mask
                const float v = valid ? s[kt][i] * 0.125f : -1e30f;  // scale 1/sqrt(64)
                s[kt][i] = v;
                mx = fmaxf(mx, v);
            }
        }
        #pragma unroll
        for (int d = 1; d < 16; d <<= 1) mx = fmaxf(mx, __shfl_xor(mx, d));
        float sum = 0.f;
        #pragma unroll
        for (int kt = 0; kt < 16; ++kt) {
            if (kt <= qt) {
                const float e = __expf(s[kt][i] - mx);
                s[kt][i] = e;
                sum += e;
            }
        }
        #pragma unroll
        for (int d = 1; d < 16; d <<= 1) sum += __shfl_xor(sum, d);
        lrow[i] = sum;
    }
    const int nks = (qt + 2) >> 1;                        // 32-wide PV k-steps
    #pragma unroll
    for (int kt = 0; kt < 16; ++kt) {                     // P -> LDS transposed (8B stores)
        if (kt < 2 * nks) {
            unsigned lo = 0, hi = 0;
            if (kt <= qt) {
                lo = (unsigned)f2bf(s[kt][0]) | ((unsigned)f2bf(s[kt][1]) << 16);
                hi = (unsigned)f2bf(s[kt][2]) | ((unsigned)f2bf(s[kt][3]) << 16);
            }
            uint2 pk; pk.x = lo; pk.y = hi;
            *(uint2*)&Pt[w][kt * 16 + fm][fq * 4] = pk;
        }
    }
    __syncthreads();
    f32x4 o[4];
    #pragma unroll
    for (int dt = 0; dt < 4; ++dt) o[dt] = (f32x4){0.f, 0.f, 0.f, 0.f};
    #pragma unroll
    for (int ks = 0; ks < 8; ++ks) {
        if (ks < nks) {
            u16x8 praw;
            #pragma unroll
            for (int j = 0; j < 8; ++j) praw[j] = Pt[w][ks * 32 + fq * 8 + j][fm];  // A-frag
            const bf16x8 pa = __builtin_bit_cast(bf16x8, praw);
            #pragma unroll
            for (int dt = 0; dt < 4; ++dt) {
                const u16* vp = Vt + ((size_t)bh * HDIM + dt * 16 + fm) * TSEQ + ks * 32 + fq * 8;
                const bf16x8 bv = __builtin_bit_cast(bf16x8, *(const u16x8*)vp);
                o[dt] = __builtin_amdgcn_mfma_f32_16x16x32_bf16(pa, bv, o[dt], 0, 0, 0);
            }
        }
    }
    #pragma unroll
    for (int i = 0; i < 4; ++i) {
        const float inv = 1.f / lrow[i];
        #pragma unroll
        for (int dt = 0; dt < 4; ++dt)
            Yb[(qrow0 + qt * 16 + fq * 4 + i) * DDIM + col0 + dt * 16 + fm] = f2bf(o[dt][i] * inv);
    }
}

extern "C" void kernel_launch(void* const* d_in, const int* in_sizes, int n_in,
                              void* d_out, int out_size, void* d_ws, size_t ws_size,
                              hipStream_t stream) {
    (void)in_sizes; (void)n_in; (void)out_size; (void)ws_size;
    const int*   idxs  = (const int*)d_in[0];
    const float* lat   = (const float*)d_in[1];
    const float* lon   = (const float*)d_in[2];
    const float* sog   = (const float*)d_in[3];
    const float* cog   = (const float*)d_in[4];
    const float* pos   = (const float*)d_in[5];
    const float* ln1_g = (const float*)d_in[6];
    const float* ln1_b = (const float*)d_in[7];
    const float* ln2_g = (const float*)d_in[8];
    const float* ln2_b = (const float*)d_in[9];
    const float* Wq = (const float*)d_in[10];
    const float* bq = (const float*)d_in[11];
    const float* Wk = (const float*)d_in[12];
    const float* bk = (const float*)d_in[13];
    const float* Wv = (const float*)d_in[14];
    const float* bv = (const float*)d_in[15];
    const float* Wo = (const float*)d_in[16];
    const float* bo = (const float*)d_in[17];
    const float* W1 = (const float*)d_in[18];
    const float* b1 = (const float*)d_in[19];
    const float* W2 = (const float*)d_in[20];
    const float* b2 = (const float*)d_in[21];
    const float* lnf_g = (const float*)d_in[22];
    const float* lnf_b = (const float*)d_in[23];
    const float* Whead = (const float*)d_in[24];

    // workspace carve (~191 MB). ub overlays qk|vt|yb (NTOK*1536 + 2*NTOK*768 == NTOK*DFF bf16).
    char* base = (char*)d_ws;
    size_t off = 0;
    auto carve = [&](size_t bytes) { void* r = base + off; off += (bytes + 255) & ~(size_t)255; return r; };
    float* h  = (float*)carve((size_t)NTOK * DDIM * 4);
    u16* xb = (u16*)carve((size_t)NTOK * DDIM * 2);
    u16* qk = (u16*)carve((size_t)NTOK * QKS * 2);    // fused Q|K
    u16* vt = (u16*)carve((size_t)NTOK * DDIM * 2);   // V^T   (must follow qk: MODE5 offsets)
    u16* yb = (u16*)carve((size_t)NTOK * DDIM * 2);
    u16* ub = qk;  // contiguous overlay [NTOK][DFF]
    u16* WtQKV = (u16*)carve((size_t)3 * DDIM * DDIM * 2);  // concat rows: Q|K|V
    u16* WtO = (u16*)carve((size_t)DDIM * DDIM * 2);
    u16* Wt1 = (u16*)carve((size_t)DDIM * DFF * 2);
    u16* Wt2 = (u16*)carve((size_t)DFF * DDIM * 2);
    u16* WtH = (u16*)carve((size_t)NOUTP * DDIM * 2);

    embed_kernel<<<NTOK * DDIM / 256, 256, 0, stream>>>(idxs, lat, lon, sog, cog, pos, h);

    // grids: blockIdx.x = M-tile (fast), blockIdx.y = N-tile
    const dim3 g768(128, 6), g3072(128, 24), gqkv(128, 18), ghead(128, 3);
    const dim3 tq4(24, 24, 4), t1(96, 24, 1), t2(24, 96, 1);
    const size_t wsq = (size_t)DDIM * DDIM, wsf = (size_t)DDIM * DFF;
    for (int l = 0; l < LNUM; ++l) {
        wconv4_kernel<<<tq4, 256, 0, stream>>>(Wq + l * wsq, Wk + l * wsq,
                                               Wv + l * wsq, Wo + l * wsq, WtQKV, WtO);
        wconv_kernel<<<t1, 256, 0, stream>>>(W1 + l * wsf, Wt1, DDIM, DFF, DFF);
        wconv_kernel<<<t2, 256, 0, stream>>>(W2 + l * wsf, Wt2, DFF, DDIM, DDIM);

        ln_kernel<<<NTOK, 256, 0, stream>>>(h, xb, ln1_g + l * DDIM, ln1_b + l * DDIM);
        gemm_bt<5><<<gqkv, 256, 0, stream>>>(xb, WtQKV, bq + l * DDIM, bk + l * DDIM,
                                             bv + l * DDIM, nullptr, qk,
                                             NTOK, 3 * DDIM, DDIM, 0);
        attn_kernel<<<dim3(768, 4), 256, 0, stream>>>(qk, vt, yb);
        gemm_bt<2><<<g768, 256, 0, stream>>>(yb, WtO, bo + l * DDIM, nullptr, nullptr, h, h,
                                             NTOK, DDIM, DDIM, 0);
        ln_kernel<<<NTOK, 256, 0, stream>>>(h, xb, ln2_g + l * DDIM, ln2_b + l * DDIM);
        gemm_bt<1><<<g3072, 256, 0, stream>>>(xb, Wt1, b1 + l * DFF, nullptr, nullptr, nullptr, ub,
                                              NTOK, DFF, DDIM, 0);
        gemm_bt<2><<<g768, 256, 0, stream>>>(ub, Wt2, b2 + l * DDIM, nullptr, nullptr, h, h,
                                             NTOK, DDIM, DFF, 0);
    }
    ln_kernel<<<NTOK, 256, 0, stream>>>(h, xb, lnf_g, lnf_b);
    wconv_kernel<<<dim3(NOUTP / 32, DDIM / 32, 1), 256, 0, stream>>>(Whead, WtH, DDIM, NOUTC, NOUTP);
    gemm_bt<3><<<ghead, 256, 0, stream>>>(xb, WtH, nullptr, nullptr, nullptr, nullptr, d_out,
                                          NTOK, NOUTP, DDIM, NOUTC);
}